// Round 12
// baseline (436.690 us; speedup 1.0000x reference)
//
#include <hip/hip_runtime.h>
#include <hip/hip_fp16.h>
#include <math.h>

#define C      4096                   // coarse buckets (M/32)
#define VPB    32                     // voxels per bucket
#define BATCH  2048                   // gaussians per hist/transform block (R12: halved for 2x grid)
#define TTPB   256                    // threads in hist/transform
#define RTPB   256                    // threads in breduce
#define GRP    16                     // lanes per voxel group
#define CAP    2048                   // bucket rows fast-path cap (mean 1024)
#define EPSF 1e-6f
#define LOG_G1 -2.3025850929940457f   /* log(0.1) */
#define LOGEPS -13.815510557964274f   /* log(1e-6) */
#define IDXMASK 0x07FFFFFFu

__device__ __forceinline__ float gsum16(float x){
  #pragma unroll
  for (int k = 8; k >= 1; k >>= 1) x += __shfl_xor(x, k, 64);
  return x;
}
__device__ __forceinline__ float gmax16(float x){
  #pragma unroll
  for (int k = 8; k >= 1; k >>= 1) x = fmaxf(x, __shfl_xor(x, k, 64));
  return x;
}
__device__ __forceinline__ float score_from(float gt, float c, float t0){
  float g0 = fmaxf(c, EPSF);
  float dt = t0 - gt;
  return fmaxf(LOG_G1 / (g0 * g0 + EPSF) * dt * dt, LOGEPS) / 0.07f;
}
__device__ __forceinline__ unsigned pack2(float a, float b){
  return (unsigned)__half_as_ushort(__float2half(a)) |
         ((unsigned)__half_as_ushort(__float2half(b)) << 16);
}
__device__ __forceinline__ float unpL(unsigned u){
  return __half2float(__ushort_as_half((unsigned short)(u & 0xFFFFu)));
}
__device__ __forceinline__ float unpH(unsigned u){
  return __half2float(__ushort_as_half((unsigned short)(u >> 16)));
}

// ---------- 1. per-block bucket histogram (LDS only) ----------
__global__ __launch_bounds__(TTPB)
void k_hist(const int* __restrict__ vox, unsigned* __restrict__ mat, int N){
  __shared__ unsigned h[C];
  for (int j = threadIdx.x; j < C; j += TTPB) h[j] = 0u;
  __syncthreads();
  size_t tbase = (size_t)blockIdx.x * BATCH;
  int nb = N - (int)tbase; if (nb > BATCH) nb = BATCH;
  for (int t = threadIdx.x; t < nb; t += TTPB)
    atomicAdd(&h[((unsigned)vox[tbase + t]) >> 5], 1u);
  __syncthreads();
  for (int j = threadIdx.x; j < C; j += TTPB)
    mat[(size_t)blockIdx.x * C + j] = h[j];
}

// ---------- 2a. parallel column-scan pass A ----------
__global__ __launch_bounds__(256)
void k_scanA(const unsigned* __restrict__ mat, unsigned* __restrict__ T,
             unsigned* __restrict__ btot, int nblk){
  int tid = threadIdx.x;
  int bl = tid >> 6, jl = tid & 63;
  int j  = blockIdx.x * 64 + jl;
  int bpt = (nblk + 3) >> 2;
  int b0 = bl * bpt, b1 = b0 + bpt; if (b1 > nblk) b1 = nblk;
  unsigned s = 0;
  for (int b = b0; b < b1; ++b) s += mat[(size_t)b * C + j];
  T[(size_t)bl * C + j] = s;
  __shared__ unsigned ts[256];
  ts[tid] = s;
  __syncthreads();
  if (bl == 0) btot[j] = ts[jl] + ts[64 + jl] + ts[128 + jl] + ts[192 + jl];
}

// ---------- 3. exclusive scan of bucket totals ----------
__global__ void k_bscan(const unsigned* __restrict__ btot, unsigned* __restrict__ bbase){
  __shared__ unsigned sm[256];
  unsigned carry = 0;
  for (int base = 0; base < C; base += 256){
    int i = base + threadIdx.x;
    unsigned v = btot[i];
    sm[threadIdx.x] = v;
    __syncthreads();
    for (int off = 1; off < 256; off <<= 1){
      unsigned t = (threadIdx.x >= off) ? sm[threadIdx.x - off] : 0u;
      __syncthreads();
      sm[threadIdx.x] += t;
      __syncthreads();
    }
    bbase[i] = carry + sm[threadIdx.x] - v;
    carry += sm[255];
    __syncthreads();
  }
}

// ---------- 2b. parallel column-scan pass B ----------
__global__ __launch_bounds__(256)
void k_scanB(unsigned* __restrict__ mat, const unsigned* __restrict__ T,
             const unsigned* __restrict__ bbase, int nblk){
  int tid = threadIdx.x;
  int bl = tid >> 6, jl = tid & 63;
  int j  = blockIdx.x * 64 + jl;
  int bpt = (nblk + 3) >> 2;
  int b0 = bl * bpt, b1 = b0 + bpt; if (b1 > nblk) b1 = nblk;
  unsigned run = bbase[j];
  for (int b2 = 0; b2 < bl; ++b2) run += T[(size_t)b2 * C + j];
  for (int b = b0; b < b1; ++b){
    unsigned o = mat[(size_t)b * C + j];
    mat[(size_t)b * C + j] = run;
    run += o;
  }
}

// ---------- 5. transform: barrier-free; direct reads, reg-packed f16 payload ----------
// payload row = 32B: 16 halfs [f0..f6, log(f7..f9), f10..f13, 0, 0]
__global__ __launch_bounds__(TTPB)
void k_transform(const float* __restrict__ feat, const float* __restrict__ conf,
                 const int* __restrict__ vox, const float* __restrict__ tt,
                 const unsigned* __restrict__ mat, float* __restrict__ S,
                 uint4* __restrict__ pay4, float2* __restrict__ pairs, int N){
  __shared__ unsigned curs[C];        // 16 KB — only LDS in this kernel
  for (int j = threadIdx.x; j < C; j += TTPB)
    curs[j] = mat[(size_t)blockIdx.x * C + j];
  __syncthreads();                    // the ONLY barrier
  float t0 = tt[0];
  size_t tbase0 = (size_t)blockIdx.x * BATCH;
  size_t iend = tbase0 + BATCH; if (iend > (size_t)N) iend = (size_t)N;
  for (size_t i = tbase0 + threadIdx.x; i < iend; i += TTPB){
    const float* fr = feat + i * 15;
    float r[15];
    #pragma unroll
    for (int c2 = 0; c2 < 15; ++c2) r[c2] = fr[c2];   // wave covers contiguous 3.84KB
    float score = score_from(r[14], conf[i], t0);
    r[7] = logf(fmaxf(r[7], 1e-6f));
    r[8] = logf(fmaxf(r[8], 1e-6f));
    r[9] = logf(fmaxf(r[9], 1e-6f));
    S[i] = score;                                     // linear
    int v = vox[i];
    unsigned gpos = atomicAdd(&curs[((unsigned)v) >> 5], 1u);   // LDS cursor
    pairs[gpos] = make_float2(score,
        __uint_as_float((unsigned)i | (((unsigned)v & 31u) << 27)));
    uint4 u0, u1;
    u0.x = pack2(r[0],  r[1]);  u0.y = pack2(r[2],  r[3]);
    u0.z = pack2(r[4],  r[5]);  u0.w = pack2(r[6],  r[7]);
    u1.x = pack2(r[8],  r[9]);  u1.y = pack2(r[10], r[11]);
    u1.z = pack2(r[12], r[13]); u1.w = 0u;
    pay4[i * 2]     = u0;                             // linear 32B/row
    pay4[i * 2 + 1] = u1;
  }
}

// ---------- 6. per-bucket reduce: LDS counting sort + 1-line gathers ----------
__global__ __launch_bounds__(RTPB)
void k_breduce(const uint4* __restrict__ pay4, const float2* __restrict__ pairs,
               const unsigned* __restrict__ bbase, const unsigned* __restrict__ btot,
               float* __restrict__ F, float* __restrict__ mArr, float* __restrict__ iArr,
               int M){
  __shared__ float          ssc[CAP];
  __shared__ unsigned       smeta[CAP];
  __shared__ unsigned short ssx[CAP];
  __shared__ unsigned lcnt[VPB + 1], lofs[VPB + 1];
  __shared__ float Fst[VPB * 15];
  __shared__ float mSt[VPB], iSt[VPB];

  int bk = blockIdx.x;
  unsigned base = bbase[bk], L = btot[bk];
  int v0 = bk * VPB;
  int g  = threadIdx.x / GRP;
  int sl = threadIdx.x & (GRP - 1);

  if (L <= CAP){
    for (unsigned j = threadIdx.x; j < L; j += RTPB){
      float2 pr = pairs[base + j];
      ssc[j]   = pr.x;
      smeta[j] = __float_as_uint(pr.y);
    }
    if (threadIdx.x <= VPB) lcnt[threadIdx.x] = 0u;
    __syncthreads();
    for (unsigned j = threadIdx.x; j < L; j += RTPB)
      atomicAdd(&lcnt[smeta[j] >> 27], 1u);
    __syncthreads();
    if (threadIdx.x == 0){
      unsigned s = 0;
      for (int k = 0; k < VPB; ++k){ lofs[k] = s; s += lcnt[k]; }
      lofs[VPB] = s;
    }
    __syncthreads();
    if (threadIdx.x < VPB) lcnt[threadIdx.x] = lofs[threadIdx.x];
    __syncthreads();
    for (unsigned j = threadIdx.x; j < L; j += RTPB){
      unsigned rk = atomicAdd(&lcnt[smeta[j] >> 27], 1u);
      ssx[rk] = (unsigned short)j;
    }
    __syncthreads();

    for (int vv = g; vv < VPB; vv += RTPB / GRP){
      unsigned s0 = lofs[vv], Lv = lofs[vv + 1] - s0;
      float m = -INFINITY;
      for (unsigned j = sl; j < Lv; j += GRP) m = fmaxf(m, ssc[ssx[s0 + j]]);
      m = gmax16(m);
      float se = 0.f, mop = -INFINITY;
      float a0=0,a1=0,a2=0,a3=0,a4=0,a5=0,a6=0,a7=0,a8=0,a9=0,a10=0,a11=0,a12=0,a13=0;
      #pragma unroll 2
      for (unsigned j = sl; j < Lv; j += GRP){
        unsigned rj  = ssx[s0 + j];
        unsigned idx = smeta[rj] & IDXMASK;
        uint4 u0 = pay4[(size_t)idx * 2];
        uint4 u1 = pay4[(size_t)idx * 2 + 1];
        float e = expf(ssc[rj] - m);
        se += e;
        float f6 = unpL(u0.w);
        mop = fmaxf(mop, f6);
        a0 += unpL(u0.x)*e;  a1 += unpH(u0.x)*e;
        a2 += unpL(u0.y)*e;  a3 += unpH(u0.y)*e;
        a4 += unpL(u0.z)*e;  a5 += unpH(u0.z)*e;
        a6 += f6*e;          a7 += unpH(u0.w)*e;
        a8 += unpL(u1.x)*e;  a9 += unpH(u1.x)*e;
        a10 += unpL(u1.y)*e; a11 += unpH(u1.y)*e;
        a12 += unpL(u1.z)*e; a13 += unpH(u1.z)*e;
      }
      se  = gsum16(se);
      a0  = gsum16(a0);  a1  = gsum16(a1);  a2  = gsum16(a2);  a3  = gsum16(a3);
      a4  = gsum16(a4);  a5  = gsum16(a5);  a6  = gsum16(a6);  a7  = gsum16(a7);
      a8  = gsum16(a8);  a9  = gsum16(a9);  a10 = gsum16(a10); a11 = gsum16(a11);
      a12 = gsum16(a12); a13 = gsum16(a13);
      mop = gmax16(mop);
      if (sl == 0){
        bool  has = (Lv > 0u);
        float inv = has ? 1.0f / se : 0.0f;
        mSt[vv] = m;  iSt[vv] = inv;
        float maxop = has ? mop : 0.0f;
        float* f = &Fst[vv * 15];
        f[0] = a0*inv; f[1] = a1*inv; f[2] = a2*inv;
        f[3] = a3*inv; f[4] = a4*inv; f[5] = a5*inv;
        f[6] = 0.7f * maxop + 0.3f * (a6*inv);
        f[7] = expf(a7*inv); f[8] = expf(a8*inv); f[9] = expf(a9*inv);
        float r0 = a10*inv, r1 = a11*inv, r2 = a12*inv, r3 = a13*inv;
        float nrm  = sqrtf(r0*r0 + r1*r1 + r2*r2 + r3*r3);
        float rinv = 1.0f / fmaxf(nrm, 1e-6f);
        f[10] = r0*rinv; f[11] = r1*rinv; f[12] = r2*rinv; f[13] = r3*rinv;
        f[14] = 0.0f;
      }
    }
  } else {
    // ---- overflow fallback (statistically never) ----
    for (int vv = g; vv < VPB; vv += RTPB / GRP){
      float m = -INFINITY;
      for (unsigned j = sl; j < L; j += GRP){
        float2 pr = pairs[base + j];
        if ((__float_as_uint(pr.y) >> 27) == (unsigned)vv) m = fmaxf(m, pr.x);
      }
      m = gmax16(m);
      float se = 0.f, mop = -INFINITY; unsigned nv = 0;
      float a0=0,a1=0,a2=0,a3=0,a4=0,a5=0,a6=0,a7=0,a8=0,a9=0,a10=0,a11=0,a12=0,a13=0;
      for (unsigned j = sl; j < L; j += GRP){
        float2 pr = pairs[base + j];
        unsigned meta = __float_as_uint(pr.y);
        if ((meta >> 27) != (unsigned)vv) continue;
        ++nv;
        unsigned idx = meta & IDXMASK;
        uint4 u0 = pay4[(size_t)idx * 2];
        uint4 u1 = pay4[(size_t)idx * 2 + 1];
        float e = expf(pr.x - m);
        se += e;
        float f6 = unpL(u0.w);
        mop = fmaxf(mop, f6);
        a0 += unpL(u0.x)*e;  a1 += unpH(u0.x)*e;
        a2 += unpL(u0.y)*e;  a3 += unpH(u0.y)*e;
        a4 += unpL(u0.z)*e;  a5 += unpH(u0.z)*e;
        a6 += f6*e;          a7 += unpH(u0.w)*e;
        a8 += unpL(u1.x)*e;  a9 += unpH(u1.x)*e;
        a10 += unpL(u1.y)*e; a11 += unpH(u1.y)*e;
        a12 += unpL(u1.z)*e; a13 += unpH(u1.z)*e;
      }
      se  = gsum16(se);
      a0  = gsum16(a0);  a1  = gsum16(a1);  a2  = gsum16(a2);  a3  = gsum16(a3);
      a4  = gsum16(a4);  a5  = gsum16(a5);  a6  = gsum16(a6);  a7  = gsum16(a7);
      a8  = gsum16(a8);  a9  = gsum16(a9);  a10 = gsum16(a10); a11 = gsum16(a11);
      a12 = gsum16(a12); a13 = gsum16(a13);
      mop = gmax16(mop);
      nv  = (unsigned)gsum16((float)nv);
      if (sl == 0){
        bool  has = (nv > 0u);
        float inv = has ? 1.0f / se : 0.0f;
        mSt[vv] = m;  iSt[vv] = inv;
        float maxop = has ? mop : 0.0f;
        float* f = &Fst[vv * 15];
        f[0] = a0*inv; f[1] = a1*inv; f[2] = a2*inv;
        f[3] = a3*inv; f[4] = a4*inv; f[5] = a5*inv;
        f[6] = 0.7f * maxop + 0.3f * (a6*inv);
        f[7] = expf(a7*inv); f[8] = expf(a8*inv); f[9] = expf(a9*inv);
        float r0 = a10*inv, r1 = a11*inv, r2 = a12*inv, r3 = a13*inv;
        float nrm  = sqrtf(r0*r0 + r1*r1 + r2*r2 + r3*r3);
        float rinv = 1.0f / fmaxf(nrm, 1e-6f);
        f[10] = r0*rinv; f[11] = r1*rinv; f[12] = r2*rinv; f[13] = r3*rinv;
        f[14] = 0.0f;
      }
    }
  }
  __syncthreads();
  int lim = M - v0; if (lim > VPB) lim = VPB;
  if (lim > 0){
    for (int j = threadIdx.x; j < lim * 15; j += RTPB)
      F[(size_t)v0 * 15 + j] = Fst[j];
    if (threadIdx.x < lim){
      mArr[v0 + threadIdx.x] = mSt[threadIdx.x];
      iArr[v0 + threadIdx.x] = iSt[threadIdx.x];
    }
  }
}

// ---------- 7. weights: all linear + L2-resident gathers ----------
__global__ void k_wfinal(const int* __restrict__ vox, const float* __restrict__ mArr,
                         const float* __restrict__ iArr, float* __restrict__ W, int N){
  int i = blockIdx.x * 256 + threadIdx.x;
  if (i >= N) return;
  int v = vox[i];
  W[i] = expf(W[i] - mArr[v]) * iArr[v];      // W held score
}

extern "C" void kernel_launch(void* const* d_in, const int* in_sizes, int n_in,
                              void* d_out, int out_size, void* d_ws, size_t ws_size,
                              hipStream_t stream) {
  const float* feat = (const float*)d_in[0];
  const int*   vox  = (const int*)  d_in[1];
  const float* tt   = (const float*)d_in[3];
  const float* conf = (const float*)d_in[4];

  int N = in_sizes[0] / 15;
  int M = (out_size - N) / 15;
  int NBLK = (N + BATCH - 1) / BATCH;

  float* F = (float*)d_out;                      // fused gaussians: M*15
  float* W = (float*)d_out + (size_t)M * 15;     // weights: N (score -> w)

  unsigned* mat   = (unsigned*)d_ws;             // NBLK*C
  unsigned* btot  = mat  + (size_t)NBLK * C;     // C
  unsigned* bbase = btot + C;                    // C
  unsigned* T     = bbase + C;                   // 4*C (slice sums)
  float*    mArr  = (float*)(T + 4 * (size_t)C); // M
  float*    iArr  = mArr + M;                    // M
  size_t head = ((size_t)NBLK * C + 6 * (size_t)C + 2 * (size_t)M + 7) & ~(size_t)7;
  unsigned* payload = (unsigned*)d_ws + head;    // 8*N u32 (32B f16 rows)
  float2*   pairs   = (float2*)(payload + (size_t)8 * N);  // N float2

  k_hist     <<<NBLK,  TTPB, 0, stream>>>(vox, mat, N);
  k_scanA    <<<C/64,  256,  0, stream>>>(mat, T, btot, NBLK);
  k_bscan    <<<1,     256,  0, stream>>>(btot, bbase);
  k_scanB    <<<C/64,  256,  0, stream>>>(mat, T, bbase, NBLK);
  k_transform<<<NBLK,  TTPB, 0, stream>>>(feat, conf, vox, tt, mat, W,
                                          (uint4*)payload, pairs, N);
  k_breduce  <<<C,     RTPB, 0, stream>>>((const uint4*)payload, pairs, bbase, btot,
                                          F, mArr, iArr, M);
  k_wfinal   <<<(N + 255)/256, 256, 0, stream>>>(vox, mArr, iArr, W, N);
}

// Round 14
// 356.323 us; speedup vs baseline: 1.2255x; 1.2255x over previous
//
#include <hip/hip_runtime.h>
#include <hip/hip_fp16.h>
#include <math.h>

#define C      4096                   // fine buckets (M/32)
#define VPB    32                     // voxels per bucket
#define BATCH  4096                   // gaussians per hist/transform block
#define TTPB   256                    // threads in hist/transform
#define RTPB   256                    // threads in breduce
#define GRP    16                     // lanes per voxel group
#define CAP    2048                   // bucket rows fast-path cap (mean 1024)
#define EPSF 1e-6f
#define LOG_G1 -2.3025850929940457f   /* log(0.1) */
#define LOGEPS -13.815510557964274f   /* log(1e-6) */
#define IDXMASK 0x07FFFFFFu

__device__ __forceinline__ float gsum16(float x){
  #pragma unroll
  for (int k = 8; k >= 1; k >>= 1) x += __shfl_xor(x, k, 64);
  return x;
}
__device__ __forceinline__ float gmax16(float x){
  #pragma unroll
  for (int k = 8; k >= 1; k >>= 1) x = fmaxf(x, __shfl_xor(x, k, 64));
  return x;
}
__device__ __forceinline__ float score_from(float gt, float c, float t0){
  float g0 = fmaxf(c, EPSF);
  float dt = t0 - gt;
  return fmaxf(LOG_G1 / (g0 * g0 + EPSF) * dt * dt, LOGEPS) / 0.07f;
}
__device__ __forceinline__ unsigned pack2(float a, float b){
  return (unsigned)__half_as_ushort(__float2half(a)) |
         ((unsigned)__half_as_ushort(__float2half(b)) << 16);
}
__device__ __forceinline__ float unpL(unsigned u){
  return __half2float(__ushort_as_half((unsigned short)(u & 0xFFFFu)));
}
__device__ __forceinline__ float unpH(unsigned u){
  return __half2float(__ushort_as_half((unsigned short)(u >> 16)));
}

// ---------- 1. per-block bucket histogram (LDS only, int4-vectorized) ----------
__global__ __launch_bounds__(TTPB)
void k_hist(const int* __restrict__ vox, unsigned* __restrict__ mat, int N){
  __shared__ unsigned h[C];
  for (int j = threadIdx.x; j < C; j += TTPB) h[j] = 0u;
  __syncthreads();
  size_t tbase = (size_t)blockIdx.x * BATCH;
  int nb = N - (int)tbase; if (nb > BATCH) nb = BATCH;
  if (nb == BATCH){
    const int4* v4 = (const int4*)(vox + tbase);
    for (int t = threadIdx.x; t < BATCH / 4; t += TTPB){
      int4 q = v4[t];
      atomicAdd(&h[((unsigned)q.x) >> 5], 1u);
      atomicAdd(&h[((unsigned)q.y) >> 5], 1u);
      atomicAdd(&h[((unsigned)q.z) >> 5], 1u);
      atomicAdd(&h[((unsigned)q.w) >> 5], 1u);
    }
  } else {
    for (int t = threadIdx.x; t < nb; t += TTPB)
      atomicAdd(&h[((unsigned)vox[tbase + t]) >> 5], 1u);
  }
  __syncthreads();
  for (int j = threadIdx.x; j < C; j += TTPB)
    mat[(size_t)blockIdx.x * C + j] = h[j];
}

// ---------- 2a. parallel column-scan pass A ----------
__global__ __launch_bounds__(256)
void k_scanA(const unsigned* __restrict__ mat, unsigned* __restrict__ T,
             unsigned* __restrict__ btot, int nblk){
  int tid = threadIdx.x;
  int bl = tid >> 6, jl = tid & 63;
  int j  = blockIdx.x * 64 + jl;
  int bpt = (nblk + 3) >> 2;
  int b0 = bl * bpt, b1 = b0 + bpt; if (b1 > nblk) b1 = nblk;
  unsigned s = 0;
  for (int b = b0; b < b1; ++b) s += mat[(size_t)b * C + j];
  T[(size_t)bl * C + j] = s;
  __shared__ unsigned ts[256];
  ts[tid] = s;
  __syncthreads();
  if (bl == 0) btot[j] = ts[jl] + ts[64 + jl] + ts[128 + jl] + ts[192 + jl];
}

// ---------- 3. exclusive scan of bucket totals ----------
__global__ void k_bscan(const unsigned* __restrict__ btot, unsigned* __restrict__ bbase){
  __shared__ unsigned sm[256];
  unsigned carry = 0;
  for (int base = 0; base < C; base += 256){
    int i = base + threadIdx.x;
    unsigned v = btot[i];
    sm[threadIdx.x] = v;
    __syncthreads();
    for (int off = 1; off < 256; off <<= 1){
      unsigned t = (threadIdx.x >= off) ? sm[threadIdx.x - off] : 0u;
      __syncthreads();
      sm[threadIdx.x] += t;
      __syncthreads();
    }
    bbase[i] = carry + sm[threadIdx.x] - v;
    carry += sm[255];
    __syncthreads();
  }
}

// ---------- 2b. parallel column-scan pass B ----------
__global__ __launch_bounds__(256)
void k_scanB(unsigned* __restrict__ mat, const unsigned* __restrict__ T,
             const unsigned* __restrict__ bbase, int nblk){
  int tid = threadIdx.x;
  int bl = tid >> 6, jl = tid & 63;
  int j  = blockIdx.x * 64 + jl;
  int bpt = (nblk + 3) >> 2;
  int b0 = bl * bpt, b1 = b0 + bpt; if (b1 > nblk) b1 = nblk;
  unsigned run = bbase[j];
  for (int b2 = 0; b2 < bl; ++b2) run += T[(size_t)b2 * C + j];
  for (int b = b0; b < b1; ++b){
    unsigned o = mat[(size_t)b * C + j];
    mat[(size_t)b * C + j] = run;
    run += o;
  }
}

// ---------- 5. transform: barrier-free; direct reads, reg-packed f16 payload ----------
// payload row = 32B: 16 halfs [f0..f6, log(f7..f9), f10..f13, 0, 0]
__global__ __launch_bounds__(TTPB)
void k_transform(const float* __restrict__ feat, const float* __restrict__ conf,
                 const int* __restrict__ vox, const float* __restrict__ tt,
                 const unsigned* __restrict__ mat, float* __restrict__ S,
                 uint4* __restrict__ pay4, float2* __restrict__ pairs, int N){
  __shared__ unsigned curs[C];        // 16 KB — only LDS in this kernel
  for (int j = threadIdx.x; j < C; j += TTPB)
    curs[j] = mat[(size_t)blockIdx.x * C + j];
  __syncthreads();                    // the ONLY barrier
  float t0 = tt[0];
  size_t tbase0 = (size_t)blockIdx.x * BATCH;
  size_t iend = tbase0 + BATCH; if (iend > (size_t)N) iend = (size_t)N;
  for (size_t i = tbase0 + threadIdx.x; i < iend; i += TTPB){
    const float* fr = feat + i * 15;
    float r[15];
    #pragma unroll
    for (int c2 = 0; c2 < 15; ++c2) r[c2] = fr[c2];   // wave covers contiguous 3.84KB
    float score = score_from(r[14], conf[i], t0);
    r[7] = logf(fmaxf(r[7], 1e-6f));
    r[8] = logf(fmaxf(r[8], 1e-6f));
    r[9] = logf(fmaxf(r[9], 1e-6f));
    S[i] = score;                                     // linear
    int v = vox[i];
    unsigned gpos = atomicAdd(&curs[((unsigned)v) >> 5], 1u);   // LDS cursor
    pairs[gpos] = make_float2(score,
        __uint_as_float((unsigned)i | (((unsigned)v & 31u) << 27)));
    uint4 u0, u1;
    u0.x = pack2(r[0],  r[1]);  u0.y = pack2(r[2],  r[3]);
    u0.z = pack2(r[4],  r[5]);  u0.w = pack2(r[6],  r[7]);
    u1.x = pack2(r[8],  r[9]);  u1.y = pack2(r[10], r[11]);
    u1.z = pack2(r[12], r[13]); u1.w = 0u;
    pay4[i * 2]     = u0;                             // linear 32B/row
    pay4[i * 2 + 1] = u1;
  }
}

// ---------- 6. per-bucket reduce: LDS counting sort + 1-line gathers ----------
__global__ __launch_bounds__(RTPB)
void k_breduce(const uint4* __restrict__ pay4, const float2* __restrict__ pairs,
               const unsigned* __restrict__ bbase, const unsigned* __restrict__ btot,
               float* __restrict__ F, float* __restrict__ mArr, float* __restrict__ iArr,
               int M){
  __shared__ float          ssc[CAP];
  __shared__ unsigned       smeta[CAP];
  __shared__ unsigned short ssx[CAP];
  __shared__ unsigned lcnt[VPB + 1], lofs[VPB + 1];
  __shared__ float Fst[VPB * 15];
  __shared__ float mSt[VPB], iSt[VPB];

  int bk = blockIdx.x;
  unsigned base = bbase[bk], L = btot[bk];
  int v0 = bk * VPB;
  int g  = threadIdx.x / GRP;
  int sl = threadIdx.x & (GRP - 1);

  if (L <= CAP){
    for (unsigned j = threadIdx.x; j < L; j += RTPB){
      float2 pr = pairs[base + j];
      ssc[j]   = pr.x;
      smeta[j] = __float_as_uint(pr.y);
    }
    if (threadIdx.x <= VPB) lcnt[threadIdx.x] = 0u;
    __syncthreads();
    for (unsigned j = threadIdx.x; j < L; j += RTPB)
      atomicAdd(&lcnt[smeta[j] >> 27], 1u);
    __syncthreads();
    if (threadIdx.x == 0){
      unsigned s = 0;
      for (int k = 0; k < VPB; ++k){ lofs[k] = s; s += lcnt[k]; }
      lofs[VPB] = s;
    }
    __syncthreads();
    if (threadIdx.x < VPB) lcnt[threadIdx.x] = lofs[threadIdx.x];
    __syncthreads();
    for (unsigned j = threadIdx.x; j < L; j += RTPB){
      unsigned rk = atomicAdd(&lcnt[smeta[j] >> 27], 1u);
      ssx[rk] = (unsigned short)j;
    }
    __syncthreads();

    for (int vv = g; vv < VPB; vv += RTPB / GRP){
      unsigned s0 = lofs[vv], Lv = lofs[vv + 1] - s0;
      float m = -INFINITY;
      for (unsigned j = sl; j < Lv; j += GRP) m = fmaxf(m, ssc[ssx[s0 + j]]);
      m = gmax16(m);
      float se = 0.f, mop = -INFINITY;
      float a0=0,a1=0,a2=0,a3=0,a4=0,a5=0,a6=0,a7=0,a8=0,a9=0,a10=0,a11=0,a12=0,a13=0;
      #pragma unroll 2
      for (unsigned j = sl; j < Lv; j += GRP){
        unsigned rj  = ssx[s0 + j];
        unsigned idx = smeta[rj] & IDXMASK;
        uint4 u0 = pay4[(size_t)idx * 2];
        uint4 u1 = pay4[(size_t)idx * 2 + 1];
        float e = expf(ssc[rj] - m);
        se += e;
        float f6 = unpL(u0.w);
        mop = fmaxf(mop, f6);
        a0 += unpL(u0.x)*e;  a1 += unpH(u0.x)*e;
        a2 += unpL(u0.y)*e;  a3 += unpH(u0.y)*e;
        a4 += unpL(u0.z)*e;  a5 += unpH(u0.z)*e;
        a6 += f6*e;          a7 += unpH(u0.w)*e;
        a8 += unpL(u1.x)*e;  a9 += unpH(u1.x)*e;
        a10 += unpL(u1.y)*e; a11 += unpH(u1.y)*e;
        a12 += unpL(u1.z)*e; a13 += unpH(u1.z)*e;
      }
      se  = gsum16(se);
      a0  = gsum16(a0);  a1  = gsum16(a1);  a2  = gsum16(a2);  a3  = gsum16(a3);
      a4  = gsum16(a4);  a5  = gsum16(a5);  a6  = gsum16(a6);  a7  = gsum16(a7);
      a8  = gsum16(a8);  a9  = gsum16(a9);  a10 = gsum16(a10); a11 = gsum16(a11);
      a12 = gsum16(a12); a13 = gsum16(a13);
      mop = gmax16(mop);
      if (sl == 0){
        bool  has = (Lv > 0u);
        float inv = has ? 1.0f / se : 0.0f;
        mSt[vv] = m;  iSt[vv] = inv;
        float maxop = has ? mop : 0.0f;
        float* f = &Fst[vv * 15];
        f[0] = a0*inv; f[1] = a1*inv; f[2] = a2*inv;
        f[3] = a3*inv; f[4] = a4*inv; f[5] = a5*inv;
        f[6] = 0.7f * maxop + 0.3f * (a6*inv);
        f[7] = expf(a7*inv); f[8] = expf(a8*inv); f[9] = expf(a9*inv);
        float r0 = a10*inv, r1 = a11*inv, r2 = a12*inv, r3 = a13*inv;
        float nrm  = sqrtf(r0*r0 + r1*r1 + r2*r2 + r3*r3);
        float rinv = 1.0f / fmaxf(nrm, 1e-6f);
        f[10] = r0*rinv; f[11] = r1*rinv; f[12] = r2*rinv; f[13] = r3*rinv;
        f[14] = 0.0f;
      }
    }
  } else {
    // ---- overflow fallback (statistically never) ----
    for (int vv = g; vv < VPB; vv += RTPB / GRP){
      float m = -INFINITY;
      for (unsigned j = sl; j < L; j += GRP){
        float2 pr = pairs[base + j];
        if ((__float_as_uint(pr.y) >> 27) == (unsigned)vv) m = fmaxf(m, pr.x);
      }
      m = gmax16(m);
      float se = 0.f, mop = -INFINITY; unsigned nv = 0;
      float a0=0,a1=0,a2=0,a3=0,a4=0,a5=0,a6=0,a7=0,a8=0,a9=0,a10=0,a11=0,a12=0,a13=0;
      for (unsigned j = sl; j < L; j += GRP){
        float2 pr = pairs[base + j];
        unsigned meta = __float_as_uint(pr.y);
        if ((meta >> 27) != (unsigned)vv) continue;
        ++nv;
        unsigned idx = meta & IDXMASK;
        uint4 u0 = pay4[(size_t)idx * 2];
        uint4 u1 = pay4[(size_t)idx * 2 + 1];
        float e = expf(pr.x - m);
        se += e;
        float f6 = unpL(u0.w);
        mop = fmaxf(mop, f6);
        a0 += unpL(u0.x)*e;  a1 += unpH(u0.x)*e;
        a2 += unpL(u0.y)*e;  a3 += unpH(u0.y)*e;
        a4 += unpL(u0.z)*e;  a5 += unpH(u0.z)*e;
        a6 += f6*e;          a7 += unpH(u0.w)*e;
        a8 += unpL(u1.x)*e;  a9 += unpH(u1.x)*e;
        a10 += unpL(u1.y)*e; a11 += unpH(u1.y)*e;
        a12 += unpL(u1.z)*e; a13 += unpH(u1.z)*e;
      }
      se  = gsum16(se);
      a0  = gsum16(a0);  a1  = gsum16(a1);  a2  = gsum16(a2);  a3  = gsum16(a3);
      a4  = gsum16(a4);  a5  = gsum16(a5);  a6  = gsum16(a6);  a7  = gsum16(a7);
      a8  = gsum16(a8);  a9  = gsum16(a9);  a10 = gsum16(a10); a11 = gsum16(a11);
      a12 = gsum16(a12); a13 = gsum16(a13);
      mop = gmax16(mop);
      nv  = (unsigned)gsum16((float)nv);
      if (sl == 0){
        bool  has = (nv > 0u);
        float inv = has ? 1.0f / se : 0.0f;
        mSt[vv] = m;  iSt[vv] = inv;
        float maxop = has ? mop : 0.0f;
        float* f = &Fst[vv * 15];
        f[0] = a0*inv; f[1] = a1*inv; f[2] = a2*inv;
        f[3] = a3*inv; f[4] = a4*inv; f[5] = a5*inv;
        f[6] = 0.7f * maxop + 0.3f * (a6*inv);
        f[7] = expf(a7*inv); f[8] = expf(a8*inv); f[9] = expf(a9*inv);
        float r0 = a10*inv, r1 = a11*inv, r2 = a12*inv, r3 = a13*inv;
        float nrm  = sqrtf(r0*r0 + r1*r1 + r2*r2 + r3*r3);
        float rinv = 1.0f / fmaxf(nrm, 1e-6f);
        f[10] = r0*rinv; f[11] = r1*rinv; f[12] = r2*rinv; f[13] = r3*rinv;
        f[14] = 0.0f;
      }
    }
  }
  __syncthreads();
  int lim = M - v0; if (lim > VPB) lim = VPB;
  if (lim > 0){
    for (int j = threadIdx.x; j < lim * 15; j += RTPB)
      F[(size_t)v0 * 15 + j] = Fst[j];
    if (threadIdx.x < lim){
      mArr[v0 + threadIdx.x] = mSt[threadIdx.x];
      iArr[v0 + threadIdx.x] = iSt[threadIdx.x];
    }
  }
}

// ---------- 7. weights: float4-vectorized linear pass + L2-resident gathers ----------
__global__ void k_wfinal(const int* __restrict__ vox, const float* __restrict__ mArr,
                         const float* __restrict__ iArr, float* __restrict__ W, int N){
  int q = blockIdx.x * 256 + threadIdx.x;       // handles 4 consecutive items
  int base = q * 4;
  if (base + 3 < N){
    float4 s = *(const float4*)(W + base);
    int4   v = *(const int4*)(vox + base);
    s.x = expf(s.x - mArr[v.x]) * iArr[v.x];
    s.y = expf(s.y - mArr[v.y]) * iArr[v.y];
    s.z = expf(s.z - mArr[v.z]) * iArr[v.z];
    s.w = expf(s.w - mArr[v.w]) * iArr[v.w];
    *(float4*)(W + base) = s;
  } else {
    for (int i = base; i < N; ++i){
      int v = vox[i];
      W[i] = expf(W[i] - mArr[v]) * iArr[v];
    }
  }
}

extern "C" void kernel_launch(void* const* d_in, const int* in_sizes, int n_in,
                              void* d_out, int out_size, void* d_ws, size_t ws_size,
                              hipStream_t stream) {
  const float* feat = (const float*)d_in[0];
  const int*   vox  = (const int*)  d_in[1];
  const float* tt   = (const float*)d_in[3];
  const float* conf = (const float*)d_in[4];

  int N = in_sizes[0] / 15;
  int M = (out_size - N) / 15;
  int NBLK = (N + BATCH - 1) / BATCH;

  float* F = (float*)d_out;                      // fused gaussians: M*15
  float* W = (float*)d_out + (size_t)M * 15;     // weights: N (score -> w)

  unsigned* mat   = (unsigned*)d_ws;             // NBLK*C
  unsigned* btot  = mat  + (size_t)NBLK * C;     // C
  unsigned* bbase = btot + C;                    // C
  unsigned* T     = bbase + C;                   // 4*C (slice sums)
  float*    mArr  = (float*)(T + 4 * (size_t)C); // M
  float*    iArr  = mArr + M;                    // M
  size_t head = ((size_t)NBLK * C + 6 * (size_t)C + 2 * (size_t)M + 7) & ~(size_t)7;
  unsigned* payload = (unsigned*)d_ws + head;    // 8*N u32 (32B f16 rows)
  float2*   pairs   = (float2*)(payload + (size_t)8 * N);  // N float2

  int gW = ((N + 3) / 4 + 255) / 256;

  k_hist     <<<NBLK,  TTPB, 0, stream>>>(vox, mat, N);
  k_scanA    <<<C/64,  256,  0, stream>>>(mat, T, btot, NBLK);
  k_bscan    <<<1,     256,  0, stream>>>(btot, bbase);
  k_scanB    <<<C/64,  256,  0, stream>>>(mat, T, bbase, NBLK);
  k_transform<<<NBLK,  TTPB, 0, stream>>>(feat, conf, vox, tt, mat, W,
                                          (uint4*)payload, pairs, N);
  k_breduce  <<<C,     RTPB, 0, stream>>>((const uint4*)payload, pairs, bbase, btot,
                                          F, mArr, iArr, M);
  k_wfinal   <<<gW, 256, 0, stream>>>(vox, mArr, iArr, W, N);
}

// Round 15
// 339.653 us; speedup vs baseline: 1.2857x; 1.0491x over previous
//
#include <hip/hip_runtime.h>
#include <hip/hip_fp16.h>
#include <math.h>

#define C      4096                   // fine buckets (M/32)
#define VPB    32                     // voxels per bucket
#define BATCH  4096                   // gaussians per hist/transform block
#define TTPB   256                    // threads in hist/transform
#define RTPB   256                    // threads in breduce
#define GRP    16                     // lanes per voxel group
#define CAP    2048                   // bucket rows fast-path cap (mean 1024)
#define EPSF 1e-6f
#define LOG_G1 -2.3025850929940457f   /* log(0.1) */
#define LOGEPS -13.815510557964274f   /* log(1e-6) */
#define IDXMASK 0x07FFFFFFu

__device__ __forceinline__ float gsum16(float x){
  #pragma unroll
  for (int k = 8; k >= 1; k >>= 1) x += __shfl_xor(x, k, 64);
  return x;
}
__device__ __forceinline__ float gmax16(float x){
  #pragma unroll
  for (int k = 8; k >= 1; k >>= 1) x = fmaxf(x, __shfl_xor(x, k, 64));
  return x;
}
__device__ __forceinline__ float score_from(float gt, float c, float t0){
  float g0 = fmaxf(c, EPSF);
  float dt = t0 - gt;
  return fmaxf(LOG_G1 / (g0 * g0 + EPSF) * dt * dt, LOGEPS) / 0.07f;
}
__device__ __forceinline__ unsigned pack2(float a, float b){
  return (unsigned)__half_as_ushort(__float2half(a)) |
         ((unsigned)__half_as_ushort(__float2half(b)) << 16);
}
__device__ __forceinline__ float unpL(unsigned u){
  return __half2float(__ushort_as_half((unsigned short)(u & 0xFFFFu)));
}
__device__ __forceinline__ float unpH(unsigned u){
  return __half2float(__ushort_as_half((unsigned short)(u >> 16)));
}

// ---------- 1. per-block bucket histogram (LDS only, int4-vectorized) ----------
__global__ __launch_bounds__(TTPB)
void k_hist(const int* __restrict__ vox, unsigned* __restrict__ mat, int N){
  __shared__ unsigned h[C];
  for (int j = threadIdx.x; j < C; j += TTPB) h[j] = 0u;
  __syncthreads();
  size_t tbase = (size_t)blockIdx.x * BATCH;
  int nb = N - (int)tbase; if (nb > BATCH) nb = BATCH;
  if (nb == BATCH){
    const int4* v4 = (const int4*)(vox + tbase);
    for (int t = threadIdx.x; t < BATCH / 4; t += TTPB){
      int4 q = v4[t];
      atomicAdd(&h[((unsigned)q.x) >> 5], 1u);
      atomicAdd(&h[((unsigned)q.y) >> 5], 1u);
      atomicAdd(&h[((unsigned)q.z) >> 5], 1u);
      atomicAdd(&h[((unsigned)q.w) >> 5], 1u);
    }
  } else {
    for (int t = threadIdx.x; t < nb; t += TTPB)
      atomicAdd(&h[((unsigned)vox[tbase + t]) >> 5], 1u);
  }
  __syncthreads();
  for (int j = threadIdx.x; j < C; j += TTPB)
    mat[(size_t)blockIdx.x * C + j] = h[j];
}

// ---------- 2a. parallel column-scan pass A: slice sums + bucket totals ----------
__global__ __launch_bounds__(256)
void k_scanA(const unsigned* __restrict__ mat, unsigned* __restrict__ T,
             unsigned* __restrict__ btot, int nblk){
  int tid = threadIdx.x;
  int bl = tid >> 6, jl = tid & 63;
  int j  = blockIdx.x * 64 + jl;
  int bpt = (nblk + 3) >> 2;
  int b0 = bl * bpt, b1 = b0 + bpt; if (b1 > nblk) b1 = nblk;
  unsigned s = 0;
  for (int b = b0; b < b1; ++b) s += mat[(size_t)b * C + j];
  T[(size_t)bl * C + j] = s;
  __shared__ unsigned ts[256];
  ts[tid] = s;
  __syncthreads();
  if (bl == 0) btot[j] = ts[jl] + ts[64 + jl] + ts[128 + jl] + ts[192 + jl];
}

// ---------- 2b. pass B (fused bscan): self-computed global prefix + offset rewrite ----------
// Each block covers 64 buckets. It redundantly computes the exclusive global
// prefix of btot (16KB L2-hot read per block) -> bbase, then rewrites mat.
__global__ __launch_bounds__(256)
void k_scanB(unsigned* __restrict__ mat, const unsigned* __restrict__ T,
             const unsigned* __restrict__ btot, unsigned* __restrict__ bbase, int nblk){
  __shared__ unsigned csum[256];     // chunk sums: chunk c = btot[16c..16c+16)
  int tid = threadIdx.x;
  // 1. chunk sums (each thread sums 16 consecutive btot entries)
  {
    const uint4* b4 = (const uint4*)(btot + tid * 16);
    unsigned s = 0;
    #pragma unroll
    for (int q = 0; q < 4; ++q){
      uint4 u = b4[q];
      s += u.x + u.y + u.z + u.w;
    }
    csum[tid] = s;
  }
  __syncthreads();
  // 2. exclusive Hillis-Steele scan of the 256 chunk sums
  unsigned own = csum[tid];
  for (int off = 1; off < 256; off <<= 1){
    unsigned t_ = (tid >= off) ? csum[tid - off] : 0u;
    __syncthreads();
    csum[tid] += t_;
    __syncthreads();
  }
  // csum[tid] is now inclusive; exclusive = inclusive - own
  __shared__ unsigned cex[256];
  cex[tid] = csum[tid] - own;
  __syncthreads();
  // 3. threads 0..63: exclusive prefix for this block's 64 buckets + mat walk
  int bl = tid >> 6, jl = tid & 63;
  int j  = blockIdx.x * 64 + jl;
  __shared__ unsigned bb[64];
  if (bl == 0){
    unsigned ex = cex[j >> 4];
    for (int k = j & ~15; k < j; ++k) ex += btot[k];
    bbase[j] = ex;
    bb[jl] = ex;
  }
  __syncthreads();
  // 4. rewrite mat column j across this thread's block-slice
  int bpt = (nblk + 3) >> 2;
  int b0 = bl * bpt, b1 = b0 + bpt; if (b1 > nblk) b1 = nblk;
  unsigned run = bb[jl];
  for (int b2 = 0; b2 < bl; ++b2) run += T[(size_t)b2 * C + j];
  for (int b = b0; b < b1; ++b){
    unsigned o = mat[(size_t)b * C + j];
    mat[(size_t)b * C + j] = run;
    run += o;
  }
}

// ---------- 3. transform: barrier-free; direct reads, reg-packed f16 payload ----------
// payload row = 32B: 16 halfs [f0..f6, log(f7..f9), f10..f13, 0, 0]
__global__ __launch_bounds__(TTPB)
void k_transform(const float* __restrict__ feat, const float* __restrict__ conf,
                 const int* __restrict__ vox, const float* __restrict__ tt,
                 const unsigned* __restrict__ mat, float* __restrict__ S,
                 uint4* __restrict__ pay4, float2* __restrict__ pairs, int N){
  __shared__ unsigned curs[C];        // 16 KB — only LDS in this kernel
  for (int j = threadIdx.x; j < C; j += TTPB)
    curs[j] = mat[(size_t)blockIdx.x * C + j];
  __syncthreads();                    // the ONLY barrier
  float t0 = tt[0];
  size_t tbase0 = (size_t)blockIdx.x * BATCH;
  size_t iend = tbase0 + BATCH; if (iend > (size_t)N) iend = (size_t)N;
  for (size_t i = tbase0 + threadIdx.x; i < iend; i += TTPB){
    const float* fr = feat + i * 15;
    float r[15];
    #pragma unroll
    for (int c2 = 0; c2 < 15; ++c2) r[c2] = fr[c2];   // wave covers contiguous 3.84KB
    float score = score_from(r[14], conf[i], t0);
    r[7] = logf(fmaxf(r[7], 1e-6f));
    r[8] = logf(fmaxf(r[8], 1e-6f));
    r[9] = logf(fmaxf(r[9], 1e-6f));
    S[i] = score;                                     // linear
    int v = vox[i];
    unsigned gpos = atomicAdd(&curs[((unsigned)v) >> 5], 1u);   // LDS cursor
    pairs[gpos] = make_float2(score,
        __uint_as_float((unsigned)i | (((unsigned)v & 31u) << 27)));
    uint4 u0, u1;
    u0.x = pack2(r[0],  r[1]);  u0.y = pack2(r[2],  r[3]);
    u0.z = pack2(r[4],  r[5]);  u0.w = pack2(r[6],  r[7]);
    u1.x = pack2(r[8],  r[9]);  u1.y = pack2(r[10], r[11]);
    u1.z = pack2(r[12], r[13]); u1.w = 0u;
    pay4[i * 2]     = u0;                             // linear 32B/row
    pay4[i * 2 + 1] = u1;
  }
}

// ---------- 4. per-bucket reduce: LDS counting sort + 1-line gathers ----------
__global__ __launch_bounds__(RTPB)
void k_breduce(const uint4* __restrict__ pay4, const float2* __restrict__ pairs,
               const unsigned* __restrict__ bbase, const unsigned* __restrict__ btot,
               float* __restrict__ F, float* __restrict__ mArr, float* __restrict__ iArr,
               int M){
  __shared__ float          ssc[CAP];
  __shared__ unsigned       smeta[CAP];
  __shared__ unsigned short ssx[CAP];
  __shared__ unsigned lcnt[VPB + 1], lofs[VPB + 1];
  __shared__ float Fst[VPB * 15];
  __shared__ float mSt[VPB], iSt[VPB];

  int bk = blockIdx.x;
  unsigned base = bbase[bk], L = btot[bk];
  int v0 = bk * VPB;
  int g  = threadIdx.x / GRP;
  int sl = threadIdx.x & (GRP - 1);

  if (L <= CAP){
    for (unsigned j = threadIdx.x; j < L; j += RTPB){
      float2 pr = pairs[base + j];
      ssc[j]   = pr.x;
      smeta[j] = __float_as_uint(pr.y);
    }
    if (threadIdx.x <= VPB) lcnt[threadIdx.x] = 0u;
    __syncthreads();
    for (unsigned j = threadIdx.x; j < L; j += RTPB)
      atomicAdd(&lcnt[smeta[j] >> 27], 1u);
    __syncthreads();
    if (threadIdx.x == 0){
      unsigned s = 0;
      for (int k = 0; k < VPB; ++k){ lofs[k] = s; s += lcnt[k]; }
      lofs[VPB] = s;
    }
    __syncthreads();
    if (threadIdx.x < VPB) lcnt[threadIdx.x] = lofs[threadIdx.x];
    __syncthreads();
    for (unsigned j = threadIdx.x; j < L; j += RTPB){
      unsigned rk = atomicAdd(&lcnt[smeta[j] >> 27], 1u);
      ssx[rk] = (unsigned short)j;
    }
    __syncthreads();

    for (int vv = g; vv < VPB; vv += RTPB / GRP){
      unsigned s0 = lofs[vv], Lv = lofs[vv + 1] - s0;
      float m = -INFINITY;
      for (unsigned j = sl; j < Lv; j += GRP) m = fmaxf(m, ssc[ssx[s0 + j]]);
      m = gmax16(m);
      float se = 0.f, mop = -INFINITY;
      float a0=0,a1=0,a2=0,a3=0,a4=0,a5=0,a6=0,a7=0,a8=0,a9=0,a10=0,a11=0,a12=0,a13=0;
      #pragma unroll 2
      for (unsigned j = sl; j < Lv; j += GRP){
        unsigned rj  = ssx[s0 + j];
        unsigned idx = smeta[rj] & IDXMASK;
        uint4 u0 = pay4[(size_t)idx * 2];
        uint4 u1 = pay4[(size_t)idx * 2 + 1];
        float e = expf(ssc[rj] - m);
        se += e;
        float f6 = unpL(u0.w);
        mop = fmaxf(mop, f6);
        a0 += unpL(u0.x)*e;  a1 += unpH(u0.x)*e;
        a2 += unpL(u0.y)*e;  a3 += unpH(u0.y)*e;
        a4 += unpL(u0.z)*e;  a5 += unpH(u0.z)*e;
        a6 += f6*e;          a7 += unpH(u0.w)*e;
        a8 += unpL(u1.x)*e;  a9 += unpH(u1.x)*e;
        a10 += unpL(u1.y)*e; a11 += unpH(u1.y)*e;
        a12 += unpL(u1.z)*e; a13 += unpH(u1.z)*e;
      }
      se  = gsum16(se);
      a0  = gsum16(a0);  a1  = gsum16(a1);  a2  = gsum16(a2);  a3  = gsum16(a3);
      a4  = gsum16(a4);  a5  = gsum16(a5);  a6  = gsum16(a6);  a7  = gsum16(a7);
      a8  = gsum16(a8);  a9  = gsum16(a9);  a10 = gsum16(a10); a11 = gsum16(a11);
      a12 = gsum16(a12); a13 = gsum16(a13);
      mop = gmax16(mop);
      if (sl == 0){
        bool  has = (Lv > 0u);
        float inv = has ? 1.0f / se : 0.0f;
        mSt[vv] = m;  iSt[vv] = inv;
        float maxop = has ? mop : 0.0f;
        float* f = &Fst[vv * 15];
        f[0] = a0*inv; f[1] = a1*inv; f[2] = a2*inv;
        f[3] = a3*inv; f[4] = a4*inv; f[5] = a5*inv;
        f[6] = 0.7f * maxop + 0.3f * (a6*inv);
        f[7] = expf(a7*inv); f[8] = expf(a8*inv); f[9] = expf(a9*inv);
        float r0 = a10*inv, r1 = a11*inv, r2 = a12*inv, r3 = a13*inv;
        float nrm  = sqrtf(r0*r0 + r1*r1 + r2*r2 + r3*r3);
        float rinv = 1.0f / fmaxf(nrm, 1e-6f);
        f[10] = r0*rinv; f[11] = r1*rinv; f[12] = r2*rinv; f[13] = r3*rinv;
        f[14] = 0.0f;
      }
    }
  } else {
    // ---- overflow fallback (statistically never) ----
    for (int vv = g; vv < VPB; vv += RTPB / GRP){
      float m = -INFINITY;
      for (unsigned j = sl; j < L; j += GRP){
        float2 pr = pairs[base + j];
        if ((__float_as_uint(pr.y) >> 27) == (unsigned)vv) m = fmaxf(m, pr.x);
      }
      m = gmax16(m);
      float se = 0.f, mop = -INFINITY; unsigned nv = 0;
      float a0=0,a1=0,a2=0,a3=0,a4=0,a5=0,a6=0,a7=0,a8=0,a9=0,a10=0,a11=0,a12=0,a13=0;
      for (unsigned j = sl; j < L; j += GRP){
        float2 pr = pairs[base + j];
        unsigned meta = __float_as_uint(pr.y);
        if ((meta >> 27) != (unsigned)vv) continue;
        ++nv;
        unsigned idx = meta & IDXMASK;
        uint4 u0 = pay4[(size_t)idx * 2];
        uint4 u1 = pay4[(size_t)idx * 2 + 1];
        float e = expf(pr.x - m);
        se += e;
        float f6 = unpL(u0.w);
        mop = fmaxf(mop, f6);
        a0 += unpL(u0.x)*e;  a1 += unpH(u0.x)*e;
        a2 += unpL(u0.y)*e;  a3 += unpH(u0.y)*e;
        a4 += unpL(u0.z)*e;  a5 += unpH(u0.z)*e;
        a6 += f6*e;          a7 += unpH(u0.w)*e;
        a8 += unpL(u1.x)*e;  a9 += unpH(u1.x)*e;
        a10 += unpL(u1.y)*e; a11 += unpH(u1.y)*e;
        a12 += unpL(u1.z)*e; a13 += unpH(u1.z)*e;
      }
      se  = gsum16(se);
      a0  = gsum16(a0);  a1  = gsum16(a1);  a2  = gsum16(a2);  a3  = gsum16(a3);
      a4  = gsum16(a4);  a5  = gsum16(a5);  a6  = gsum16(a6);  a7  = gsum16(a7);
      a8  = gsum16(a8);  a9  = gsum16(a9);  a10 = gsum16(a10); a11 = gsum16(a11);
      a12 = gsum16(a12); a13 = gsum16(a13);
      mop = gmax16(mop);
      nv  = (unsigned)gsum16((float)nv);
      if (sl == 0){
        bool  has = (nv > 0u);
        float inv = has ? 1.0f / se : 0.0f;
        mSt[vv] = m;  iSt[vv] = inv;
        float maxop = has ? mop : 0.0f;
        float* f = &Fst[vv * 15];
        f[0] = a0*inv; f[1] = a1*inv; f[2] = a2*inv;
        f[3] = a3*inv; f[4] = a4*inv; f[5] = a5*inv;
        f[6] = 0.7f * maxop + 0.3f * (a6*inv);
        f[7] = expf(a7*inv); f[8] = expf(a8*inv); f[9] = expf(a9*inv);
        float r0 = a10*inv, r1 = a11*inv, r2 = a12*inv, r3 = a13*inv;
        float nrm  = sqrtf(r0*r0 + r1*r1 + r2*r2 + r3*r3);
        float rinv = 1.0f / fmaxf(nrm, 1e-6f);
        f[10] = r0*rinv; f[11] = r1*rinv; f[12] = r2*rinv; f[13] = r3*rinv;
        f[14] = 0.0f;
      }
    }
  }
  __syncthreads();
  int lim = M - v0; if (lim > VPB) lim = VPB;
  if (lim > 0){
    for (int j = threadIdx.x; j < lim * 15; j += RTPB)
      F[(size_t)v0 * 15 + j] = Fst[j];
    if (threadIdx.x < lim){
      mArr[v0 + threadIdx.x] = mSt[threadIdx.x];
      iArr[v0 + threadIdx.x] = iSt[threadIdx.x];
    }
  }
}

// ---------- 5. weights: float4-vectorized linear pass + L2-resident gathers ----------
__global__ void k_wfinal(const int* __restrict__ vox, const float* __restrict__ mArr,
                         const float* __restrict__ iArr, float* __restrict__ W, int N){
  int q = blockIdx.x * 256 + threadIdx.x;       // handles 4 consecutive items
  int base = q * 4;
  if (base + 3 < N){
    float4 s = *(const float4*)(W + base);
    int4   v = *(const int4*)(vox + base);
    s.x = expf(s.x - mArr[v.x]) * iArr[v.x];
    s.y = expf(s.y - mArr[v.y]) * iArr[v.y];
    s.z = expf(s.z - mArr[v.z]) * iArr[v.z];
    s.w = expf(s.w - mArr[v.w]) * iArr[v.w];
    *(float4*)(W + base) = s;
  } else {
    for (int i = base; i < N; ++i){
      int v = vox[i];
      W[i] = expf(W[i] - mArr[v]) * iArr[v];
    }
  }
}

extern "C" void kernel_launch(void* const* d_in, const int* in_sizes, int n_in,
                              void* d_out, int out_size, void* d_ws, size_t ws_size,
                              hipStream_t stream) {
  const float* feat = (const float*)d_in[0];
  const int*   vox  = (const int*)  d_in[1];
  const float* tt   = (const float*)d_in[3];
  const float* conf = (const float*)d_in[4];

  int N = in_sizes[0] / 15;
  int M = (out_size - N) / 15;
  int NBLK = (N + BATCH - 1) / BATCH;

  float* F = (float*)d_out;                      // fused gaussians: M*15
  float* W = (float*)d_out + (size_t)M * 15;     // weights: N (score -> w)

  unsigned* mat   = (unsigned*)d_ws;             // NBLK*C
  unsigned* btot  = mat  + (size_t)NBLK * C;     // C
  unsigned* bbase = btot + C;                    // C
  unsigned* T     = bbase + C;                   // 4*C (slice sums)
  float*    mArr  = (float*)(T + 4 * (size_t)C); // M
  float*    iArr  = mArr + M;                    // M
  size_t head = ((size_t)NBLK * C + 6 * (size_t)C + 2 * (size_t)M + 7) & ~(size_t)7;
  unsigned* payload = (unsigned*)d_ws + head;    // 8*N u32 (32B f16 rows)
  float2*   pairs   = (float2*)(payload + (size_t)8 * N);  // N float2

  int gW = ((N + 3) / 4 + 255) / 256;

  k_hist     <<<NBLK,  TTPB, 0, stream>>>(vox, mat, N);
  k_scanA    <<<C/64,  256,  0, stream>>>(mat, T, btot, NBLK);
  k_scanB    <<<C/64,  256,  0, stream>>>(mat, T, btot, bbase, NBLK);
  k_transform<<<NBLK,  TTPB, 0, stream>>>(feat, conf, vox, tt, mat, W,
                                          (uint4*)payload, pairs, N);
  k_breduce  <<<C,     RTPB, 0, stream>>>((const uint4*)payload, pairs, bbase, btot,
                                          F, mArr, iArr, M);
  k_wfinal   <<<gW, 256, 0, stream>>>(vox, mArr, iArr, W, N);
}